// Round 4
// baseline (944.908 us; speedup 1.0000x reference)
//
#include <hip/hip_runtime.h>
#include <hip/hip_bf16.h>

#define N_NODES 32768
#define F_IN    32
#define HC      64
#define HEADS   4
#define NE      524288
#define NET     (NE + N_NODES)   /* 557056 = 2176*256 */
#define NG      64
#define TT      512
#define OUTF    24

__device__ __forceinline__ float lrelu(float x){ return x > 0.f ? x : 0.2f*x; }
__device__ __forceinline__ float eluf (float x){ return x > 0.f ? x : __expf(x)-1.f; }
__device__ __forceinline__ float sigmf(float x){ return 1.f/(1.f+__expf(-x)); }
__device__ __forceinline__ float tanhfast(float x){ return 1.f - 2.f/(__expf(2.f*x)+1.f); }
__device__ __forceinline__ float bcast(float v, int k){
  return __int_as_float(__builtin_amdgcn_readlane(__float_as_int(v), k));
}
// Pin a loaded value into a register: definition becomes this asm, so the
// pre-RA remat/sink stage cannot push the load back into the loop.
__device__ __forceinline__ void pin4(float4 &v){
  asm volatile("" : "+v"(v.x), "+v"(v.y), "+v"(v.z), "+v"(v.w));
}

// ---------------- CSR build: incoming-edge lists per destination ----------------
__global__ __launch_bounds__(256) void k_deg(const int* __restrict__ ei,
                                             int* __restrict__ deg){
  int e = blockIdx.x*256 + threadIdx.x;   // e < NET
  int d = (e < NE) ? ei[NE+e] : (e - NE);
  atomicAdd(deg + d, 1);
}

__global__ __launch_bounds__(1024) void k_scan(const int* __restrict__ deg,
                                               int* __restrict__ rowptr){
  __shared__ int ps[1024];
  const int t = threadIdx.x;
  const int base = t*32;
  int local[32]; int s = 0;
  #pragma unroll
  for(int i=0;i<32;i++){ local[i]=deg[base+i]; s+=local[i]; }
  ps[t]=s; __syncthreads();
  for(int off=1; off<1024; off<<=1){
    int v = (t>=off) ? ps[t-off] : 0;
    __syncthreads();
    ps[t]+=v;
    __syncthreads();
  }
  int run = (t==0) ? 0 : ps[t-1];
  #pragma unroll
  for(int i=0;i<32;i++){ rowptr[base+i]=run; run+=local[i]; }
  if(t==1023) rowptr[N_NODES]=run;
}

__global__ __launch_bounds__(256) void k_fill(const int* __restrict__ ei,
                                              const int* __restrict__ rowptr,
                                              int* __restrict__ cur,
                                              int* __restrict__ col){
  int e = blockIdx.x*256 + threadIdx.x;   // e < NET
  int s, d;
  if(e < NE){ s = ei[e]; d = ei[NE+e]; } else { s = e-NE; d = s; }
  int pos = atomicAdd(cur + d, 1);
  col[rowptr[d] + pos] = s;
}

// ---------------- GAT layer 1, restructured (h1 never materialized) ----------------
__global__ __launch_bounds__(256) void k_alpha1x(const float* __restrict__ x,
                                                 const float* __restrict__ W1,
                                                 const float* __restrict__ a_src,
                                                 const float* __restrict__ a_dst,
                                                 float* __restrict__ as1,
                                                 float* __restrict__ ad1){
  __shared__ float ps[256];
  const int tid = threadIdx.x;
  {
    const int k = tid>>3, q = tid&7;
    const int h = q>>1, isd = q&1;
    const float* av = (isd ? a_dst : a_src) + h*64;
    const float* wr = W1 + k*256 + h*64;
    float acc = 0.f;
    #pragma unroll
    for(int c=0;c<64;c++) acc += wr[c]*av[c];
    ps[(isd?128:0) + k*4 + h] = acc;
  }
  __syncthreads();
  const int n = blockIdx.x*256 + tid;
  const float4* xr = (const float4*)(x + n*32);
  float sa0=0.f,sa1=0.f,sa2=0.f,sa3=0.f, sd0=0.f,sd1=0.f,sd2=0.f,sd3=0.f;
  #pragma unroll
  for(int k4=0;k4<8;k4++){
    float4 v = xr[k4];
    const float* pa = ps + (4*k4)*4;
    const float* pd = ps + 128 + (4*k4)*4;
    sa0 += v.x*pa[0] + v.y*pa[4] + v.z*pa[8]  + v.w*pa[12];
    sa1 += v.x*pa[1] + v.y*pa[5] + v.z*pa[9]  + v.w*pa[13];
    sa2 += v.x*pa[2] + v.y*pa[6] + v.z*pa[10] + v.w*pa[14];
    sa3 += v.x*pa[3] + v.y*pa[7] + v.z*pa[11] + v.w*pa[15];
    sd0 += v.x*pd[0] + v.y*pd[4] + v.z*pd[8]  + v.w*pd[12];
    sd1 += v.x*pd[1] + v.y*pd[5] + v.z*pd[9]  + v.w*pd[13];
    sd2 += v.x*pd[2] + v.y*pd[6] + v.z*pd[10] + v.w*pd[14];
    sd3 += v.x*pd[3] + v.y*pd[7] + v.z*pd[11] + v.w*pd[15];
  }
  *(float4*)(as1+n*4) = make_float4(sa0,sa1,sa2,sa3);
  *(float4*)(ad1+n*4) = make_float4(sd0,sd1,sd2,sd3);
}

// aggregate x per (node, head): agg[d,h,k] = sum_e w_e^h x[src_e,k]; s14 = sum w.
__global__ __launch_bounds__(256) void k_gatx(const int* __restrict__ rowptr,
                                              const int* __restrict__ col,
                                              const float* __restrict__ as1,
                                              const float* __restrict__ ad1,
                                              const float* __restrict__ x,
                                              float* __restrict__ agg,
                                              float* __restrict__ s14){
  const int node = blockIdx.x*4 + (threadIdx.x>>6);
  const int lane = threadIdx.x & 63;
  const int h0   = lane>>5;                  // 0 or 1
  const int c    = lane & 31;
  const int beg = rowptr[node], end = rowptr[node+1];
  const float adA = ad1[node*4 + h0];
  const float adB = ad1[node*4 + h0 + 2];
  float accA=0.f, accB=0.f, wsA=0.f, wsB=0.f;
  int j = beg;
  for(; j+3 < end; j += 4){
    int s0 = col[j], s1 = col[j+1], s2 = col[j+2], s3 = col[j+3];
    float4 q0 = *(const float4*)(as1 + s0*4);
    float4 q1 = *(const float4*)(as1 + s1*4);
    float4 q2 = *(const float4*)(as1 + s2*4);
    float4 q3 = *(const float4*)(as1 + s3*4);
    float x0 = x[s0*32 + c];
    float x1 = x[s1*32 + c];
    float x2 = x[s2*32 + c];
    float x3 = x[s3*32 + c];
    float wA0 = __expf(lrelu((h0?q0.y:q0.x) + adA));
    float wA1 = __expf(lrelu((h0?q1.y:q1.x) + adA));
    float wA2 = __expf(lrelu((h0?q2.y:q2.x) + adA));
    float wA3 = __expf(lrelu((h0?q3.y:q3.x) + adA));
    float wB0 = __expf(lrelu((h0?q0.w:q0.z) + adB));
    float wB1 = __expf(lrelu((h0?q1.w:q1.z) + adB));
    float wB2 = __expf(lrelu((h0?q2.w:q2.z) + adB));
    float wB3 = __expf(lrelu((h0?q3.w:q3.z) + adB));
    accA += wA0*x0 + wA1*x1 + wA2*x2 + wA3*x3;
    accB += wB0*x0 + wB1*x1 + wB2*x2 + wB3*x3;
    wsA  += (wA0+wA1) + (wA2+wA3);
    wsB  += (wB0+wB1) + (wB2+wB3);
  }
  for(; j < end; j++){
    int s0 = col[j];
    float4 q0 = *(const float4*)(as1 + s0*4);
    float wA0 = __expf(lrelu((h0?q0.y:q0.x) + adA));
    float wB0 = __expf(lrelu((h0?q0.w:q0.z) + adB));
    float x0 = x[s0*32 + c];
    accA += wA0*x0; accB += wB0*x0;
    wsA += wA0; wsB += wB0;
  }
  agg[node*128 + h0*32 + c]     = accA;
  agg[node*128 + (h0+2)*32 + c] = accB;
  if(c == 0){
    s14[node*4 + h0]     = wsA;
    s14[node*4 + h0 + 2] = wsB;
  }
}

// Fused: out1 = ELU(agg@W1/s + b1) [LDS only] ; h2 = out1@W2 ; as2/ad2 from h2.
__global__ __launch_bounds__(256) void k_g12(const float* __restrict__ agg,
                                             const float* __restrict__ W1,
                                             const float* __restrict__ s14,
                                             const float* __restrict__ b1,
                                             const float* __restrict__ W2,
                                             const float* __restrict__ a_src2,
                                             const float* __restrict__ a_dst2,
                                             float* __restrict__ h2,
                                             float* __restrict__ as2,
                                             float* __restrict__ ad2){
  __shared__ __align__(16) float ags[32*128];   // 16KB; reused as h2 tile
  __shared__ __align__(16) float o1s[32*256];   // 32KB
  __shared__ float sv[128];
  const int tid  = threadIdx.x;
  const int row0 = blockIdx.x*32;
  const float4* ag = (const float4*)(agg + (size_t)row0*128);
  float4* a4 = (float4*)ags;
  for(int i=tid;i<1024;i+=256) a4[i]=ag[i];
  if(tid<32) ((float4*)sv)[tid]=((const float4*)(s14+row0*4))[tid];
  float wc[32];
  #pragma unroll
  for(int k=0;k<32;k++) wc[k]=W1[k*256+tid];
  const float bb=b1[tid];
  __syncthreads();
  const int h = tid>>6;
  for(int r=0;r<32;r++){
    const float4* ar=(const float4*)(ags + r*128 + h*32);
    float acc=0.f;
    #pragma unroll
    for(int k4=0;k4<8;k4++){
      float4 v=ar[k4];
      acc += v.x*wc[4*k4]+v.y*wc[4*k4+1]+v.z*wc[4*k4+2]+v.w*wc[4*k4+3];
    }
    float inv = 1.f/(sv[r*4+h] + 1e-16f);
    o1s[r*256+tid] = eluf(acc*inv + bb);
  }
  __syncthreads();
  const int c0=(tid&15)*4;
  const int r0=(tid>>4)*2;
  float acc2[2][4]={};
  for(int k=0;k<256;k+=4){
    float wv[4][4];
    #pragma unroll
    for(int i=0;i<4;i++){
      float4 w=*(const float4*)(W2+(k+i)*64+c0);
      wv[i][0]=w.x; wv[i][1]=w.y; wv[i][2]=w.z; wv[i][3]=w.w;
    }
    #pragma unroll
    for(int i=0;i<2;i++){
      float4 xv=*(const float4*)(o1s+(r0+i)*256+k);
      #pragma unroll
      for(int j=0;j<4;j++)
        acc2[i][j]+=xv.x*wv[0][j]+xv.y*wv[1][j]+xv.z*wv[2][j]+xv.w*wv[3][j];
    }
  }
  float* h2s = ags;
  #pragma unroll
  for(int i=0;i<2;i++){
    float4 o = make_float4(acc2[i][0],acc2[i][1],acc2[i][2],acc2[i][3]);
    *(float4*)(h2 + (size_t)(row0+r0+i)*64 + c0) = o;
    *(float4*)(h2s + (r0+i)*64 + c0) = o;
  }
  __syncthreads();
  if(tid < 32){
    const float4* hp=(const float4*)(h2s + tid*64);
    float sa=0.f, sd=0.f;
    #pragma unroll
    for(int i=0;i<16;i++){
      float4 v=hp[i];
      float4 a=((const float4*)a_src2)[i];
      float4 d=((const float4*)a_dst2)[i];
      sa+=v.x*a.x+v.y*a.y+v.z*a.z+v.w*a.w;
      sd+=v.x*d.x+v.y*d.y+v.z*d.z+v.w*d.w;
    }
    as2[row0+tid]=sa; ad2[row0+tid]=sd;
  }
}

// fused gather layer 2: one wave per node, lane = channel; 4-wide unrolled.
__global__ __launch_bounds__(256) void k_gat2(const int* __restrict__ rowptr,
                                              const int* __restrict__ col,
                                              const float* __restrict__ as2,
                                              const float* __restrict__ ad2,
                                              const float* __restrict__ h2,
                                              const float* __restrict__ b2,
                                              float* __restrict__ out2){
  const int node = blockIdx.x*4 + (threadIdx.x>>6);
  const int lane = threadIdx.x & 63;
  const int beg = rowptr[node], end = rowptr[node+1];
  const float ad = ad2[node];
  float acc = 0.f, s = 0.f;
  int j = beg;
  for(; j+3 < end; j += 4){
    int s0 = col[j], s1 = col[j+1], s2 = col[j+2], s3 = col[j+3];
    float a0 = as2[s0], a1 = as2[s1], a2 = as2[s2], a3 = as2[s3];
    float v0 = h2[s0*64+lane], v1 = h2[s1*64+lane];
    float v2 = h2[s2*64+lane], v3 = h2[s3*64+lane];
    float w0 = __expf(lrelu(a0 + ad));
    float w1 = __expf(lrelu(a1 + ad));
    float w2 = __expf(lrelu(a2 + ad));
    float w3 = __expf(lrelu(a3 + ad));
    acc += w0*v0 + w1*v1 + w2*v2 + w3*v3;
    s += (w0+w1) + (w2+w3);
  }
  for(; j < end; j++){
    int s0 = col[j];
    float w0 = __expf(lrelu(as2[s0] + ad));
    acc += w0*h2[s0*64+lane];
    s += w0;
  }
  const float inv = 1.f/(s + 1e-16f);
  out2[node*64+lane] = eluf(acc*inv + b2[lane]);
}

// ---------------- GRU input GEMM: gi = in @ Wih^T + bih   [N,64]@[64,192] ----------------
__global__ __launch_bounds__(256) void k_gemm_gi(const float* __restrict__ in,
                                                 const float* __restrict__ Wih,
                                                 const float* __restrict__ bih,
                                                 float* __restrict__ gi){
  __shared__ __align__(16) float xs[64*64];
  __shared__ float wT[64*192];
  const int tid=threadIdx.x;
  const int row0=blockIdx.x*64;
  const float4* xg=(const float4*)(in+row0*64);
  float4* xs4=(float4*)xs;
  for(int i=tid;i<1024;i+=256) xs4[i]=xg[i];
  for(int i=tid;i<12288;i+=256){ wT[(i&63)*192+(i>>6)] = Wih[i]; }
  __syncthreads();
  if(tid<192){
    float wr[64];
    #pragma unroll
    for(int k=0;k<64;k++) wr[k]=wT[k*192+tid];
    const float bj=bih[tid];
    for(int r=0;r<64;r++){
      float acc=bj;
      const float4* xr=(const float4*)(xs+r*64);
      #pragma unroll
      for(int k4=0;k4<16;k4++){
        float4 v=xr[k4];
        acc+=v.x*wr[4*k4]+v.y*wr[4*k4+1]+v.z*wr[4*k4+2]+v.w*wr[4*k4+3];
      }
      gi[(row0+r)*192+tid]=acc;
    }
  }
}

// ---------------- Single-wave, barrier-free GRU layer pass ----------------
// Round-2 post-mortem: three different phase-A structures all ran at the same
// ~1950 cyc/step -> the invariant cost is the 2-barriers + 2 LDS round-trips
// per step of the multi-wave pipeline (at 1 block/CU there is no co-resident
// work to hide barrier arrival skew). This kernel removes ALL synchronization:
// one wave per graph; lane l holds h[l] in a register; readlane broadcasts h
// without LDS; lane l computes gh[l], gh[64+l], gh[128+l] (192 FMA + 64
// readlane); the gate for element l is lane-local. W rows = 192 VGPRs, within
// the 512-VGPR budget at 1 wave/EU. gi is prefetched 2 steps ahead.
#define GRU_W_LOAD(W)                                             \
  const float4* pa = (const float4*)((W) + lane*64);              \
  const float4* pb = (const float4*)((W) + (64+lane)*64);         \
  const float4* pc = (const float4*)((W) + (128+lane)*64);        \
  float4 Av0=pa[0], Av1=pa[1], Av2=pa[2],  Av3=pa[3];             \
  float4 Av4=pa[4], Av5=pa[5], Av6=pa[6],  Av7=pa[7];             \
  float4 Av8=pa[8], Av9=pa[9], AvA=pa[10], AvB=pa[11];            \
  float4 AvC=pa[12],AvD=pa[13],AvE=pa[14], AvF=pa[15];            \
  float4 Bv0=pb[0], Bv1=pb[1], Bv2=pb[2],  Bv3=pb[3];             \
  float4 Bv4=pb[4], Bv5=pb[5], Bv6=pb[6],  Bv7=pb[7];             \
  float4 Bv8=pb[8], Bv9=pb[9], BvA=pb[10], BvB=pb[11];            \
  float4 BvC=pb[12],BvD=pb[13],BvE=pb[14], BvF=pb[15];            \
  float4 Cv0=pc[0], Cv1=pc[1], Cv2=pc[2],  Cv3=pc[3];             \
  float4 Cv4=pc[4], Cv5=pc[5], Cv6=pc[6],  Cv7=pc[7];             \
  float4 Cv8=pc[8], Cv9=pc[9], CvA=pc[10], CvB=pc[11];            \
  float4 CvC=pc[12],CvD=pc[13],CvE=pc[14], CvF=pc[15];            \
  pin4(Av0);pin4(Av1);pin4(Av2);pin4(Av3);pin4(Av4);pin4(Av5);    \
  pin4(Av6);pin4(Av7);pin4(Av8);pin4(Av9);pin4(AvA);pin4(AvB);    \
  pin4(AvC);pin4(AvD);pin4(AvE);pin4(AvF);                        \
  pin4(Bv0);pin4(Bv1);pin4(Bv2);pin4(Bv3);pin4(Bv4);pin4(Bv5);    \
  pin4(Bv6);pin4(Bv7);pin4(Bv8);pin4(Bv9);pin4(BvA);pin4(BvB);    \
  pin4(BvC);pin4(BvD);pin4(BvE);pin4(BvF);                        \
  pin4(Cv0);pin4(Cv1);pin4(Cv2);pin4(Cv3);pin4(Cv4);pin4(Cv5);    \
  pin4(Cv6);pin4(Cv7);pin4(Cv8);pin4(Cv9);pin4(CvA);pin4(CvB);    \
  pin4(CvC);pin4(CvD);pin4(CvE);pin4(CvF);

#define DOT4S(WA, WB, WC, BASE) {                                                   \
  float t0=bcast(hv,BASE+0), t1=bcast(hv,BASE+1), t2=bcast(hv,BASE+2), t3=bcast(hv,BASE+3); \
  a0 = fmaf(t0, WA.x, a0);  b0 = fmaf(t0, WB.x, b0);  c0 = fmaf(t0, WC.x, c0);      \
  a1 = fmaf(t1, WA.y, a1);  b1 = fmaf(t1, WB.y, b1);  c1 = fmaf(t1, WC.y, c1);      \
  a2 = fmaf(t2, WA.z, a2);  b2 = fmaf(t2, WB.z, b2);  c2 = fmaf(t2, WC.z, c2);      \
  a3 = fmaf(t3, WA.w, a3);  b3 = fmaf(t3, WB.w, b3);  c3 = fmaf(t3, WC.w, c3); }

#define GRU_MATVEC()                                                  \
  float a0=biasA, a1=0.f, a2=0.f, a3=0.f;                             \
  float b0=biasB, b1=0.f, b2=0.f, b3=0.f;                             \
  float c0=biasC, c1=0.f, c2=0.f, c3=0.f;                             \
  float hv = h;                                                       \
  DOT4S(Av0,Bv0,Cv0, 0)  DOT4S(Av1,Bv1,Cv1, 4)                        \
  DOT4S(Av2,Bv2,Cv2, 8)  DOT4S(Av3,Bv3,Cv3, 12)                       \
  DOT4S(Av4,Bv4,Cv4, 16) DOT4S(Av5,Bv5,Cv5, 20)                       \
  DOT4S(Av6,Bv6,Cv6, 24) DOT4S(Av7,Bv7,Cv7, 28)                       \
  DOT4S(Av8,Bv8,Cv8, 32) DOT4S(Av9,Bv9,Cv9, 36)                       \
  DOT4S(AvA,BvA,CvA, 40) DOT4S(AvB,BvB,CvB, 44)                       \
  DOT4S(AvC,BvC,CvC, 48) DOT4S(AvD,BvD,CvD, 52)                       \
  DOT4S(AvE,BvE,CvE, 56) DOT4S(AvF,BvF,CvF, 60)                       \
  float ghA=(a0+a1)+(a2+a3);                                          \
  float ghB=(b0+b1)+(b2+b3);                                          \
  float ghC=(c0+c1)+(c2+c3);

__global__ __launch_bounds__(64,1) void k_gru_l1(const float* __restrict__ gi1,
                                                 const float* __restrict__ Whh,
                                                 const float* __restrict__ bhh,
                                                 float* __restrict__ seq){
  const int lane = threadIdx.x;
  const int b    = blockIdx.x;
  const float* gib = gi1 + (size_t)b*TT*192;
  GRU_W_LOAD(Whh)
  const float biasA = bhh[lane];
  const float biasB = bhh[64+lane];
  const float biasC = bhh[128+lane];
  float h = 0.f;
  float gA = gib[lane],       gB = gib[64+lane],       gC = gib[128+lane];
  float nA = gib[192+lane],   nB = gib[192+64+lane],   nC = gib[192+128+lane];
  float* sq = seq + (size_t)b*TT*64 + lane;
  for(int t=0;t<TT;t++){
    float fA=0.f, fB=0.f, fC=0.f;
    if(t+2 < TT){
      const float* g2 = gib + (size_t)(t+2)*192;
      fA = g2[lane]; fB = g2[64+lane]; fC = g2[128+lane];
    }
    GRU_MATVEC()
    float r = sigmf(gA + ghA);
    float z = sigmf(gB + ghB);
    float n = tanhfast(gC + r*ghC);
    h = (1.f-z)*n + z*h;
    sq[(size_t)t*64] = h;
    gA = nA; gB = nB; gC = nC;
    nA = fA; nB = fB; nC = fC;
  }
}

__global__ __launch_bounds__(64,1) void k_gru_l2(const float* __restrict__ gi2,
                                                 const float* __restrict__ Whh,
                                                 const float* __restrict__ bhh,
                                                 const float* __restrict__ Wl,
                                                 const float* __restrict__ bl,
                                                 float* __restrict__ fout){
  __shared__ float hf[64];
  const int lane = threadIdx.x;
  const int b    = blockIdx.x;
  const float* gib = gi2 + (size_t)b*TT*192;
  GRU_W_LOAD(Whh)
  const float biasA = bhh[lane];
  const float biasB = bhh[64+lane];
  const float biasC = bhh[128+lane];
  float h = 0.f;
  float gA = gib[lane],       gB = gib[64+lane],       gC = gib[128+lane];
  float nA = gib[192+lane],   nB = gib[192+64+lane],   nC = gib[192+128+lane];
  for(int t=0;t<TT;t++){
    float fA=0.f, fB=0.f, fC=0.f;
    if(t+2 < TT){
      const float* g2 = gib + (size_t)(t+2)*192;
      fA = g2[lane]; fB = g2[64+lane]; fC = g2[128+lane];
    }
    GRU_MATVEC()
    float r = sigmf(gA + ghA);
    float z = sigmf(gB + ghB);
    float n = tanhfast(gC + r*ghC);
    h = (1.f-z)*n + z*h;
    gA = nA; gB = nB; gC = nC;
    nA = fA; nB = fB; nC = fC;
  }
  hf[lane] = h;
  __syncthreads();
  if(lane < 24){
    float acc = bl[lane];
    const float4* wl4 = (const float4*)(Wl + lane*64);
    #pragma unroll
    for(int k4=0;k4<16;k4++){
      float4 h4 = *(const float4*)(hf + 4*k4);
      float4 w4 = wl4[k4];
      acc += h4.x*w4.x + h4.y*w4.y + h4.z*w4.z + h4.w*w4.w;
    }
    fout[b*24+lane] = acc;
  }
}

extern "C" void kernel_launch(void* const* d_in, const int* in_sizes, int n_in,
                              void* d_out, int out_size, void* d_ws, size_t ws_size,
                              hipStream_t stream){
  const float* x     =(const float*)d_in[0];
  const int*   ei    =(const int*  )d_in[1];
  const float* W1    =(const float*)d_in[3];
  const float* a_src1=(const float*)d_in[4];
  const float* a_dst1=(const float*)d_in[5];
  const float* b1    =(const float*)d_in[6];
  const float* W2    =(const float*)d_in[7];
  const float* a_src2=(const float*)d_in[8];
  const float* a_dst2=(const float*)d_in[9];
  const float* b2    =(const float*)d_in[10];
  const float* Wih0  =(const float*)d_in[11];
  const float* Whh0  =(const float*)d_in[12];
  const float* bih0  =(const float*)d_in[13];
  const float* bhh0  =(const float*)d_in[14];
  const float* Wih1  =(const float*)d_in[15];
  const float* Whh1  =(const float*)d_in[16];
  const float* bih1  =(const float*)d_in[17];
  const float* bhh1  =(const float*)d_in[18];
  const float* Wl    =(const float*)d_in[19];
  const float* bl    =(const float*)d_in[20];

  float* ws   = (float*)d_ws;
  float* agg  = ws;                  // 4194304 [N,128] (dead after k_g12)
  float* s14  = ws + 4194304;        // 131072 [N,4]
  float* gi1  = ws;                  // [N,192] overwrites agg after it's dead
  float* out2 = ws + 8388608;        // 2097152 (k_gat2 output; dead after k_gemm_gi)
  float* seq  = ws + 8388608;        // [N,64] layer-1 GRU outputs (reuses out2? NO - see below)
  float* gi2  = ws + 10485760;       // [N,192] 6291456 floats (ends at 16777216)
  float* h2   = ws + 16777216;       // 2097152
  float* as1  = ws + 18874368;       // 131072
  float* ad1  = as1 + 131072;        // 131072
  float* as2  = ad1 + 131072;        // 32768
  float* ad2  = as2 + 32768;         // 32768
  int* rowptr = (int*)(ad2 + 32768); // 32769 (padded to 32800)
  int* deg    = rowptr + 32800;      // 32768
  int* cur    = deg + 32768;         // 32768 (contiguous with deg: one memset)
  int* col    = cur + 32768;         // 557056
  float* fo   = (float*)d_out;
  // NOTE: seq aliases out2. out2 is the input of the FIRST k_gemm_gi (gi1);
  // k_gru_l1 reads only gi1 and writes seq -> out2 must stay live through
  // k_gemm_gi (it does: k_gemm_gi runs before k_gru_l1). seq region [8388608,
  // 10485760) is written by k_gru_l1 and read by the second k_gemm_gi. OK.

  hipMemsetAsync(deg, 0, 2*32768*sizeof(int), stream);  // deg + cur

  k_deg   <<<2176,256,0,stream>>>(ei,deg);
  k_scan  <<<1  ,1024,0,stream>>>(deg,rowptr);
  k_fill  <<<2176,256,0,stream>>>(ei,rowptr,cur,col);

  k_alpha1x<<<128 ,256,0,stream>>>(x,W1,a_src1,a_dst1,as1,ad1);
  k_gatx   <<<8192,256,0,stream>>>(rowptr,col,as1,ad1,x,agg,s14);
  k_g12    <<<1024,256,0,stream>>>(agg,W1,s14,b1,W2,a_src2,a_dst2,h2,as2,ad2);
  k_gat2   <<<8192,256,0,stream>>>(rowptr,col,as2,ad2,h2,b2,out2);
  k_gemm_gi<<<512 ,256,0,stream>>>(out2,Wih0,bih0,gi1);
  k_gru_l1 <<<64  ,64 ,0,stream>>>(gi1,Whh0,bhh0,seq);
  k_gemm_gi<<<512 ,256,0,stream>>>(seq,Wih1,bih1,gi2);
  k_gru_l2 <<<64  ,64 ,0,stream>>>(gi2,Whh1,bhh1,Wl,bl,fo);
  (void)in_sizes; (void)n_in; (void)out_size; (void)ws_size;
}